// Round 6
// baseline (326.220 us; speedup 1.0000x reference)
//
#include <hip/hip_runtime.h>

#define NB 4
#define NS 2048
#define ND 512
#define NH 8
#define NDK 64

typedef __attribute__((ext_vector_type(8))) short bf16x8;
typedef __attribute__((ext_vector_type(4))) short bf16x4;
typedef __attribute__((ext_vector_type(4))) float f32x4;
typedef __attribute__((ext_vector_type(4))) int   i32x4;

__device__ inline f32x4 mfma16(bf16x8 a, bf16x8 b, f32x4 c) {
    return __builtin_amdgcn_mfma_f32_16x16x32_bf16(a, b, c, 0, 0, 0);
}
__device__ inline unsigned short f2bf(float f) {
    unsigned u = __float_as_uint(f);
    unsigned r = u + 0x7FFFu + ((u >> 16) & 1u);
    return (unsigned short)(r >> 16);
}
__device__ inline float bf2f(unsigned short h) {
    return __uint_as_float(((unsigned)h) << 16);
}
__device__ inline void splitf(float x, short& hi, short& lo) {
    unsigned short h = f2bf(x);
    hi = (short)h;
    lo = (short)f2bf(x - bf2f(h));
}
__device__ inline float exp2_fast(float x) {
    float r; asm("v_exp_f32 %0, %1" : "=v"(r) : "v"(x)); return r;
}
__device__ inline void gload16(const void* g, void* l) {
    __builtin_amdgcn_global_load_lds(
        (const __attribute__((address_space(1))) unsigned int*)g,
        (__attribute__((address_space(3))) unsigned int*)l, 16, 0, 0);
}

// ---------------------------------------------------------------------------
// prep_split: X f32 -> hi/lo bf16 planes (elementwise, coalesced).
// ---------------------------------------------------------------------------
__global__ __launch_bounds__(256) void prep_split(
    const float* __restrict__ X, short* __restrict__ xh, short* __restrict__ xl)
{
    int i = (blockIdx.x * 256 + threadIdx.x) * 4;
    float4 f = *(const float4*)(X + i);
    short h0,h1,h2,h3,l0,l1,l2,l3;
    splitf(f.x,h0,l0); splitf(f.y,h1,l1); splitf(f.z,h2,l2); splitf(f.w,h3,l3);
    bf16x4 hv = {h0,h1,h2,h3}, lv = {l0,l1,l2,l3};
    *(bf16x4*)(xh + i) = hv;
    *(bf16x4*)(xl + i) = lv;
}

// ---------------------------------------------------------------------------
// prep_w: weights -> B-layout planes [n=h*64+dk][k=d], split bf16 hi/lo for
// WQ/WK, single bf16 for WV. Planes live in d_out (dead before oproj).
// ---------------------------------------------------------------------------
__global__ __launch_bounds__(256) void prep_w(
    const float* __restrict__ WQ, const float* __restrict__ WK,
    const float* __restrict__ WV,
    short* __restrict__ wqh, short* __restrict__ wql,
    short* __restrict__ wkh, short* __restrict__ wkl, short* __restrict__ wv)
{
    const int z = blockIdx.y;
    const int gid = blockIdx.x * 256 + threadIdx.x;
    const int idx = gid * 4;
    const int dk = idx & 63;
    const int d  = (idx >> 6) & 511;
    const int h  = idx >> 15;
    const float* src = ((z == 0) ? WQ : (z == 1) ? WK : WV) + idx;
    float4 f = *(const float4*)src;
    size_t o = (size_t)(h * 64 + dk) * 512 + d;
    if (z < 2) {
        short* oh = z ? wkh : wqh;
        short* ol = z ? wkl : wql;
        short hh, ll;
        splitf(f.x, hh, ll); oh[o]        = hh; ol[o]        = ll;
        splitf(f.y, hh, ll); oh[o +  512] = hh; ol[o +  512] = ll;
        splitf(f.z, hh, ll); oh[o + 1024] = hh; ol[o + 1024] = ll;
        splitf(f.w, hh, ll); oh[o + 1536] = hh; ol[o + 1536] = ll;
    } else {
        wv[o]        = (short)f2bf(f.x);
        wv[o +  512] = (short)f2bf(f.y);
        wv[o + 1024] = (short)f2bf(f.z);
        wv[o + 1536] = (short)f2bf(f.w);
    }
}

// ---------------------------------------------------------------------------
// proj v3: tile 128m x 128n, K=512, 4 waves (2x2), each 64x64 (acc 4x4).
// XCD-grouped grid: i -> x=i&7 (XCD), j=i>>3; nb=j&3, group=(j>>2)*8+x;
// mt=group&63, z=zbase+(group>>6). The 4 nb-blocks of one (mt,z) are
// dispatch-adjacent on ONE XCD -> X m-tile read once into that L2.
// X staged via global_load_lds from pre-split planes, pre-swizzled source
// (chunk j stored at jj = j ^ (row&3)); W fragments direct from L2 planes.
// z=2 (V): stages raw f32 V with in-reg cvt (T14 split), single-term MFMA.
// ---------------------------------------------------------------------------
__global__ __launch_bounds__(256, 3) void proj(
    const short* __restrict__ xph, const short* __restrict__ xpl,
    const float* __restrict__ Vf,
    const short* __restrict__ wqh, const short* __restrict__ wql,
    const short* __restrict__ wkh, const short* __restrict__ wkl,
    const short* __restrict__ wvp,
    short* __restrict__ qth, short* __restrict__ qtl,
    short* __restrict__ kth, short* __restrict__ ktl,
    short* __restrict__ vt, int zbase)
{
    const int i = blockIdx.x;
    const int xcd = i & 7, jj_ = i >> 3;
    const int nb4 = jj_ & 3, gl = jj_ >> 2;
    const int grp = gl * 8 + xcd;
    const int mt = grp & 63;
    const int z  = zbase + (grp >> 6);
    const int m0 = mt * 128, nb = nb4 * 128;
    const int tid = threadIdx.x;
    const int w = tid >> 6, lane = tid & 63, c = lane & 15, gq = lane >> 4;
    const int wm = w >> 1, wn = w & 1;

    const short* Wh = (z == 0) ? wqh : (z == 1) ? wkh : wvp;
    const short* Wl = (z == 0) ? wql : wkl;

    __shared__ __align__(16) short smem[17408];   // 34,816 B
    char* smem8 = (char*)smem;
    // X dbuf bytes: buf b: xh @ b*16384, xl @ b*16384+8192

    f32x4 acc[4][4];
    #pragma unroll
    for (int a = 0; a < 4; a++)
        #pragma unroll
        for (int b = 0; b < 4; b++) acc[a][b] = f32x4{0.f,0.f,0.f,0.f};

    const int rowl = lane >> 2;                  // 0..15
    const int jsw  = (lane & 3) ^ (rowl & 3);    // pre-swizzled source chunk
    const int xorc = (c & 3) << 4;

    auto STAGE_G = [&](int buf, int k0) {        // z<2: 4 KB per wave via DMA
        size_t rb = (size_t)(m0 + w*32 + rowl) * 1024 + (size_t)k0 * 2 + jsw * 16;
        char* db = smem8 + buf*16384 + w*2048;
        gload16((const char*)xph + rb,         db);
        gload16((const char*)xph + rb + 16384, db + 1024);
        gload16((const char*)xpl + rb,         db + 8192);
        gload16((const char*)xpl + rb + 16384, db + 9216);
    };

    const int r_ = tid >> 1, kqs = (tid & 1) * 16;
    float4 fv0, fv1, fv2, fv3;
    auto VLOAD = [&](int k0) {
        const float* s = Vf + (size_t)(m0 + r_) * ND + k0 + kqs;
        fv0 = ((const float4*)s)[0]; fv1 = ((const float4*)s)[1];
        fv2 = ((const float4*)s)[2]; fv3 = ((const float4*)s)[3];
    };
    auto VWRITE = [&](int buf) {
        short t[16];
        t[0]=(short)f2bf(fv0.x);  t[1]=(short)f2bf(fv0.y);
        t[2]=(short)f2bf(fv0.z);  t[3]=(short)f2bf(fv0.w);
        t[4]=(short)f2bf(fv1.x);  t[5]=(short)f2bf(fv1.y);
        t[6]=(short)f2bf(fv1.z);  t[7]=(short)f2bf(fv1.w);
        t[8]=(short)f2bf(fv2.x);  t[9]=(short)f2bf(fv2.y);
        t[10]=(short)f2bf(fv2.z); t[11]=(short)f2bf(fv2.w);
        t[12]=(short)f2bf(fv3.x); t[13]=(short)f2bf(fv3.y);
        t[14]=(short)f2bf(fv3.z); t[15]=(short)f2bf(fv3.w);
        bf16x8 a, b;
        #pragma unroll
        for (int q = 0; q < 8; q++) { a[q] = t[q]; b[q] = t[8+q]; }
        char* bp = smem8 + buf*16384 + r_*64;
        int x0 = ((tid & 1) * 32) ^ ((r_ & 3) << 4);
        *(bf16x8*)(bp + x0)        = a;
        *(bf16x8*)(bp + (x0 ^ 16)) = b;
    };

    auto COMPUTE = [&](int buf, int k0) {
        const char* xb = smem8 + buf*16384;
        bf16x8 ah[4], al[4];
        #pragma unroll
        for (int mi = 0; mi < 4; mi++) {
            int off = (64*wm + 16*mi + c)*64 + ((16*gq) ^ xorc);
            ah[mi] = *(const bf16x8*)(xb + off);
            if (z < 2) al[mi] = *(const bf16x8*)(xb + 8192 + off);
        }
        const short* wr  = Wh + (size_t)(nb + 64*wn + c) * 512 + k0 + 8*gq;
        const short* wr2 = (z < 2) ? (Wl + (size_t)(nb + 64*wn + c) * 512 + k0 + 8*gq) : wr;
        #pragma unroll
        for (int nf = 0; nf < 4; nf++) {
            bf16x8 bh = *(const bf16x8*)(wr + nf*16*512);
            if (z < 2) {
                bf16x8 bl = *(const bf16x8*)(wr2 + nf*16*512);
                #pragma unroll
                for (int mi = 0; mi < 4; mi++) {
                    acc[mi][nf] = mfma16(ah[mi], bh, acc[mi][nf]);
                    acc[mi][nf] = mfma16(ah[mi], bl, acc[mi][nf]);
                    acc[mi][nf] = mfma16(al[mi], bh, acc[mi][nf]);
                }
            } else {
                #pragma unroll
                for (int mi = 0; mi < 4; mi++)
                    acc[mi][nf] = mfma16(ah[mi], bh, acc[mi][nf]);
            }
        }
    };

    if (z < 2) STAGE_G(0, 0); else { VLOAD(0); VWRITE(0); }
    int cur = 0;
    for (int it = 0; it < 16; ++it) {
        int k0 = it * 32;
        __syncthreads();
        if (it < 15) { if (z < 2) STAGE_G(cur ^ 1, k0 + 32); else VLOAD(k0 + 32); }
        COMPUTE(cur, k0);
        if (z == 2 && it < 15) VWRITE(cur ^ 1);
        cur ^= 1;
    }

    // ---- epilogue: through-LDS transpose to swizzled 8KB tiles ----
    const int bbase = (m0 >> 11) * NH;
    const int sbase = m0 & 2047;
    short* ep = smem;   // [128][136]
    if (z < 2) {
        #pragma unroll
        for (int pass = 0; pass < 2; pass++) {
            __syncthreads();
            #pragma unroll
            for (int mi = 0; mi < 4; mi++)
                #pragma unroll
                for (int nf = 0; nf < 4; nf++)
                    #pragma unroll
                    for (int r = 0; r < 4; r++) {
                        int rl  = 64*wm + 16*mi + 4*gq + r;
                        int col = 64*wn + 16*nf + c;
                        short hh, ll; splitf(acc[mi][nf][r], hh, ll);
                        ep[rl*136 + col] = pass ? ll : hh;
                    }
            __syncthreads();
            int rl2 = tid >> 1, half = tid & 1;
            int head = nb4 * 2 + half;
            int s = sbase + rl2;
            int t = s >> 6, sr = s & 63, sw2 = (sr & 7) << 4;
            short* dst = pass ? (z ? ktl : qtl) : (z ? kth : qth);
            char* base = (char*)dst + ((size_t)(bbase + head) * 32 + t) * 8192 + sr * 128;
            const short* row = &ep[rl2*136 + half*64];
            #pragma unroll
            for (int ch = 0; ch < 8; ch++)
                *(bf16x8*)(base + ((ch*16) ^ sw2)) = *(const bf16x8*)(row + ch*8);
        }
    } else {
        __syncthreads();
        #pragma unroll
        for (int mi = 0; mi < 4; mi++)
            #pragma unroll
            for (int nf = 0; nf < 4; nf++)
                #pragma unroll
                for (int r = 0; r < 4; r++) {
                    int rl  = 64*wm + 16*mi + 4*gq + r;
                    int col = 64*wn + 16*nf + c;
                    ep[rl*136 + col] = (short)f2bf(acc[mi][nf][r]);
                }
        __syncthreads();
        int col = tid >> 1, tt = tid & 1;
        int head = nb4 * 2 + (col >> 6), dk = col & 63;
        int s0_ = sbase + tt * 64;
        int t = s0_ >> 6;
        char* base = (char*)vt + ((size_t)(bbase + head) * 32 + t) * 8192 + dk * 128;
        int sw2 = (dk & 7) << 4;
        #pragma unroll
        for (int ch = 0; ch < 8; ch++) {
            bf16x8 vv;
            #pragma unroll
            for (int q = 0; q < 8; q++) vv[q] = ep[(tt*64 + ch*8 + q)*136 + col];
            *(bf16x8*)(base + ((ch*16) ^ sw2)) = vv;
        }
    }
}

// ---------------------------------------------------------------------------
// attn_kernel: flash attention, 64 q-rows/block. HI-FIRST QK^T: hi*hi scores
// (8 MFMA) -> approx tile-max -> skip decision; only live tiles pay the 16
// correction MFMAs + softmax + PV. Approx-max error absorbed by defer-max
// headroom. Register-staged K/V pipeline; swizzled zero-conflict LDS.
// ---------------------------------------------------------------------------
__global__ __launch_bounds__(256, 4) void attn_kernel(
    const short* __restrict__ qth, const short* __restrict__ qtl,
    const short* __restrict__ kth, const short* __restrict__ ktl,
    const short* __restrict__ vtl, short* __restrict__ ao)
{
    const int orig = blockIdx.x;
    const int wg = (orig & 7) * 128 + (orig >> 3);
    const int bh = wg >> 5, qb = (wg & 31) * 64;
    const int tid = threadIdx.x;
    const int w = tid >> 6, lane = tid & 63, c = lane & 15, g = lane >> 4;

    __shared__ __align__(16) short kh_s[64*64];
    __shared__ __align__(16) short kl_s[64*64];
    __shared__ __align__(16) short v_s [64*64];
    __shared__ __align__(16) short pb  [4][16*64];
    char* khb = (char*)kh_s;
    char* klb = (char*)kl_s;
    char* vb  = (char*)v_s;
    char* pwb = (char*)pb[w];
    short* pw = pb[w];

    bf16x8 qh[2], ql[2];
    {
        const char* qtbh = (const char*)qth + ((size_t)bh*32 + (qb>>6))*8192;
        const char* qtbl = (const char*)qtl + ((size_t)bh*32 + (qb>>6))*8192;
        int s_in = 16*w + c;
        int sw = (s_in & 7) << 4;
        qh[0] = *(const bf16x8*)(qtbh + s_in*128 + ((16*g) ^ sw));
        qh[1] = *(const bf16x8*)(qtbh + s_in*128 + ((64 + 16*g) ^ sw));
        ql[0] = *(const bf16x8*)(qtbl + s_in*128 + ((16*g) ^ sw));
        ql[1] = *(const bf16x8*)(qtbl + s_in*128 + ((64 + 16*g) ^ sw));
    }

    const char* kg = (const char*)kth + (size_t)bh * 262144;
    const char* lg = (const char*)ktl + (size_t)bh * 262144;
    const char* vg = (const char*)vtl + (size_t)bh * 262144;
    const int thr = w * 2048 + lane * 16;

    const float SC = 0.18033688f;   // 0.125 * log2(e)
    float mrow[4], lrowp[4];
    f32x4 acc[4];
    #pragma unroll
    for (int r = 0; r < 4; r++) { mrow[r] = -1e30f; lrowp[r] = 0.f; }
    #pragma unroll
    for (int nf = 0; nf < 4; nf++) acc[nf] = f32x4{0.f,0.f,0.f,0.f};

    i32x4 s0, s1, s2, s3, s4, s5;
    {
        const char* p = kg + thr; s0 = *(const i32x4*)p; s1 = *(const i32x4*)(p + 1024);
        p = lg + thr;             s2 = *(const i32x4*)p; s3 = *(const i32x4*)(p + 1024);
        p = vg + thr;             s4 = *(const i32x4*)p; s5 = *(const i32x4*)(p + 1024);
    }

    for (int t = 0; t < 32; ++t) {
        {   // publish staged regs -> LDS
            char* d = khb + thr; *(i32x4*)d = s0; *(i32x4*)(d + 1024) = s1;
            d = klb + thr;       *(i32x4*)d = s2; *(i32x4*)(d + 1024) = s3;
            d = vb + thr;        *(i32x4*)d = s4; *(i32x4*)(d + 1024) = s5;
        }
        __syncthreads();
        if (t < 31) {   // prefetch next tile into regs (hides under compute)
            size_t off = (size_t)(t + 1) * 8192 + thr;
            const char* p = kg + off; s0 = *(const i32x4*)p; s1 = *(const i32x4*)(p + 1024);
            p = lg + off;             s2 = *(const i32x4*)p; s3 = *(const i32x4*)(p + 1024);
            p = vg + off;             s4 = *(const i32x4*)p; s5 = *(const i32x4*)(p + 1024);
        }

        // ---- HI-only scores first (8 MFMA) ----
        f32x4 s4c[4];
        __builtin_amdgcn_s_setprio(1);
        #pragma unroll
        for (int sf = 0; sf < 4; sf++) {
            s4c[sf] = f32x4{0.f,0.f,0.f,0.f};
            int rowK = c + 16*sf;
            #pragma unroll
            for (int ks = 0; ks < 2; ks++) {
                int cb = (ks*64 + 16*g) ^ ((rowK & 7) << 4);
                bf16x8 kh = *(bf16x8*)(khb + rowK*128 + cb);
                s4c[sf] = mfma16(qh[ks], kh, s4c[sf]);
            }
        }
        __builtin_amdgcn_s_setprio(0);

        // approx per-row tile max (raw domain; err ~ +-4 raw, harmless)
        float tmax[4];
        #pragma unroll
        for (int r = 0; r < 4; r++) {
            float v = fmaxf(fmaxf(s4c[0][r], s4c[1][r]), fmaxf(s4c[2][r], s4c[3][r]));
            #pragma unroll
            for (int off = 1; off < 16; off <<= 1) v = fmaxf(v, __shfl_xor(v, off));
            tmax[r] = v;
        }
        float dmax = fmaxf(fmaxf(tmax[0]-mrow[0], tmax[1]-mrow[1]),
                           fmaxf(tmax[2]-mrow[2], tmax[3]-mrow[3]));
        if (!__all(dmax < -140.0f)) {
            // ---- correction terms (live tiles only): qh*kl + ql*kh ----
            __builtin_amdgcn_s_setprio(1);
            #pragma unroll
            for (int sf = 0; sf < 4; sf++) {
                int rowK = c + 16*sf;
                #pragma unroll
                for (int ks = 0; ks < 2; ks++) {
                    int cb = (ks*64 + 16*g) ^ ((rowK & 7) << 4);
                    bf16x8 kh = *(bf16x8*)(khb + rowK*128 + cb);
                    bf16x8 kl = *(bf16x8*)(klb + rowK*128 + cb);
                    s4c[sf] = mfma16(qh[ks], kl, s4c[sf]);
                    s4c[sf] = mfma16(ql[ks], kh, s4c[sf]);
                }
            }
            __builtin_amdgcn_s_setprio(0);

            if (__any(dmax > 64.0f)) {   // defer-max rescale
                #pragma unroll
                for (int r = 0; r < 4; r++) {
                    float mn = fmaxf(mrow[r], tmax[r]);
                    float fc = exp2_fast((mrow[r] - mn) * SC);
                    mrow[r] = mn; lrowp[r] *= fc;
                    acc[0][r] *= fc; acc[1][r] *= fc; acc[2][r] *= fc; acc[3][r] *= fc;
                }
            }
            float mS[4];
            #pragma unroll
            for (int r = 0; r < 4; r++) mS[r] = mrow[r] * SC;
            float rs[4] = {0.f, 0.f, 0.f, 0.f};
            #pragma unroll
            for (int sf = 0; sf < 4; sf++) {
                #pragma unroll
                for (int r = 0; r < 4; r++) {
                    float p = exp2_fast(fmaf(s4c[sf][r], SC, -mS[r]));
                    rs[r] += p;
                    int q = 4*g + r;
                    *(short*)(pwb + q*128 + ((2*c + 32*sf) ^ ((q & 7) << 4))) =
                        (short)(__float_as_uint(p) >> 16);
                }
            }
            #pragma unroll
            for (int r = 0; r < 4; r++) lrowp[r] += rs[r];

            // PV
            __builtin_amdgcn_s_setprio(1);
            #pragma unroll
            for (int ks = 0; ks < 2; ks++) {
                int cbp = (ks*64 + 16*g) ^ ((c & 7) << 4);
                bf16x8 pa = *(bf16x8*)(pwb + c*128 + cbp);
                #pragma unroll
                for (int nf = 0; nf < 4; nf++) {
                    int rowV = c + 16*nf;
                    int cbv = (ks*64 + 16*g) ^ ((rowV & 7) << 4);
                    bf16x8 vv = *(bf16x8*)(vb + rowV*128 + cbv);
                    acc[nf] = mfma16(pa, vv, acc[nf]);
                }
            }
            __builtin_amdgcn_s_setprio(0);
        }
        __syncthreads();
    }

    float inv[4];
    #pragma unroll
    for (int r = 0; r < 4; r++) {
        float t2 = lrowp[r];
        #pragma unroll
        for (int off = 1; off < 16; off <<= 1) t2 += __shfl_xor(t2, off);
        inv[r] = 1.f / t2;
    }
    #pragma unroll
    for (int nf = 0; nf < 4; nf++)
        #pragma unroll
        for (int r = 0; r < 4; r++)
            pw[(4*g + r)*64 + c + 16*nf] = (short)f2bf(acc[nf][r] * inv[r]);

    const int b = bh >> 3, hh = bh & 7;
    {
        int q = qb + 16*w + c;
        size_t o = ((size_t)b * NS + q) * ND + hh * NDK + g * 16;
        const short* src = pw + c*64 + g*16;
        *(bf16x8*)&ao[o]     = *(const bf16x8*)src;
        *(bf16x8*)&ao[o + 8] = *(const bf16x8*)(src + 8);
    }
}

// ---------------------------------------------------------------------------
// oproj v3: out[8192x512] = ao(bf16) @ WO(f32). Tile 128x128, XCD-grouped,
// ao via global_load_lds (pre-swizzled src), W^T staged per-iter via in-reg
// 4x4 transpose (float4 -> 4x b64), double-buffered, direct f32 stores.
// ---------------------------------------------------------------------------
__global__ __launch_bounds__(256) void oproj(
    const short* __restrict__ ao, const float* __restrict__ WO, float* __restrict__ out)
{
    const int i = blockIdx.x;
    const int xcd = i & 7, jj_ = i >> 3;
    const int nb4 = jj_ & 3, gl = jj_ >> 2;
    const int mt = gl * 8 + xcd;
    const int m0 = mt * 128, nb = nb4 * 128;
    const int tid = threadIdx.x;
    const int w = tid >> 6, lane = tid & 63, c = lane & 15, gq = lane >> 4;
    const int wm = w >> 1, wn = w & 1;

    __shared__ __align__(16) short smem[18432];   // ao dbuf 16KB + wt dbuf 20KB
    char* smem8 = (char*)smem;
    short* wt0 = smem + 8192;

    f32x4 acc[4][4];
    #pragma unroll
    for (int a = 0; a < 4; a++)
        #pragma unroll
        for (int b = 0; b < 4; b++) acc[a][b] = f32x4{0.f,0.f,0.f,0.f};

    const int rowl = lane >> 2;
    const int jsw  = (lane & 3) ^ (rowl & 3);
    const int xorc = (c & 3) << 4;

    auto STAGE_A = [&](int buf, int k0) {
        size_t rb = (size_t)(m0 + w*32 + rowl) * 1024 + (size_t)k0 * 2 + jsw * 16;
        char* db = smem8 + buf*8192 + w*2048;
        gload16((const char*)ao + rb,         db);
        gload16((const char*)ao + rb + 16384, db + 1024);
    };

    const int kg = tid >> 5, ng = tid & 31;
    float4 wf0, wf1, wf2, wf3;
    auto WLOAD = [&](int k0) {
        const float* s = WO + (size_t)(k0 + kg*4) * 512 + nb + ng*4;
        wf0 = *(const float4*)s;
        wf1 = *(const float4*)(s + 512);
        wf2 = *(const float4*)(s + 1024);
        wf3 = *(const float4*)(s + 1536);
    };
    auto WWRITE = [&](int buf) {
        short* wb = wt0 + buf*5120;
        bf16x4 c0 = {(short)f2bf(wf0.x),(short)f2bf(wf1.x),(short)f2bf(wf2.x),(short)f2bf(wf3.x)};
        bf16x4 c1 = {(short)f2bf(wf0.y),(short)f2bf(wf1.y),(short)f2bf(wf2.y),(short)f2bf(wf3.y)};
        bf16x4 c2 = {(short)f2bf(wf0.z),(short)f2bf(wf1.z),(short)f2bf(wf2.z),(short)f2bf(wf3.z)};
        bf16x4 c3 = {(short)f2bf(wf0.w),(short)f2bf(wf1.w),(short)f2bf(wf2.w),(short)f2bf(wf3.w)};
        *(bf16x4*)&wb[(ng*4 + 0)*40 + kg*4] = c0;
        *(bf16x4*)&wb[(ng*4 + 1)*40 + kg*4] = c1;
        *(bf16x4*)&wb[(ng*4 + 2)*40 + kg*4] = c2;
        *(bf16x4*)&wb[(ng*4 + 3)*40 + kg*4] = c3;
    };

    auto COMPUTE = [&](int buf) {
        const char* ab = smem8 + buf*8192;
        const short* wb = wt0 + buf*5120;
        bf16x8 ah[4];
        #pragma unroll
        for (int mi = 0; mi < 4; mi++)
            ah[mi] = *(const bf16x8*)(ab + (64*wm + 16*mi + c)*64 + ((16*gq) ^ xorc));
        #pragma unroll
        for (int nf = 0; nf < 4; nf++) {
            bf16x8 bh = *(const bf16x8*)&wb[(64*wn + 16*nf + c)*40 + 8*gq];
            #pragma unroll
            for (int mi = 0; mi < 4; mi++)
                acc[mi][nf] = mfma16(ah[mi], bh, acc[mi][nf]);
        }
    };

    WLOAD(0); STAGE_A(0, 0); WWRITE(0);
    int cur = 0;
    for (int it = 0; it < 16; ++it) {
        __syncthreads();
        if (it < 15) { STAGE_A(cur ^ 1, it*32 + 32); WLOAD(it*32 + 32); }
        COMPUTE(cur);
        if (it < 15) WWRITE(cur ^ 1);
        cur ^= 1;
    }

    #pragma unroll
    for (int mi = 0; mi < 4; mi++)
        #pragma unroll
        for (int nf = 0; nf < 4; nf++)
            #pragma unroll
            for (int r = 0; r < 4; r++) {
                int row = m0 + 64*wm + 16*mi + 4*gq + r;
                out[(size_t)row * ND + nb + 64*wn + 16*nf + c] = acc[mi][nf][r];
            }
}

extern "C" void kernel_launch(void* const* d_in, const int* in_sizes, int n_in,
                              void* d_out, int out_size, void* d_ws, size_t ws_size,
                              hipStream_t stream) {
    (void)in_sizes; (void)n_in; (void)out_size; (void)ws_size;
    const float* Q  = (const float*)d_in[0];
    const float* K  = (const float*)d_in[1];
    const float* V  = (const float*)d_in[2];
    const float* WQ = (const float*)d_in[3];
    const float* WK = (const float*)d_in[4];
    const float* WV = (const float*)d_in[5];
    const float* WO = (const float*)d_in[6];

    char* ws = (char*)d_ws;
    const size_t PLANE = (size_t)NB * NH * NS * NDK * 2;   // 8,388,608 B (x6 = proven 50.3 MB)
    short* qth = (short*)(ws);
    short* qtl = (short*)(ws +     PLANE);
    short* kth = (short*)(ws + 2 * PLANE);
    short* ktl = (short*)(ws + 3 * PLANE);
    short* xh  = (short*)(ws + 4 * PLANE);   // X hi plane; later ao
    short* xl  = (short*)(ws + 5 * PLANE);   // X lo plane
    short* ao  = xh;

    // d_out scratch: weight planes (2.62 MB) + vt (8 MB @ 3 MB); all dead
    // before oproj overwrites d_out.
    short* wqh = (short*)d_out;
    short* wql = wqh + 262144;
    short* wkh = wqh + 2 * 262144;
    short* wkl = wqh + 3 * 262144;
    short* wv  = wqh + 4 * 262144;
    short* vt  = (short*)((char*)d_out + 3145728);

    prep_w<<<dim3(256, 3), 256, 0, stream>>>(WQ, WK, WV, wqh, wql, wkh, wkl, wv);
    prep_split<<<4096, 256, 0, stream>>>(Q, xh, xl);
    proj<<<256, 256, 0, stream>>>(xh, xl, V, wqh, wql, wkh, wkl, wv,
                                  qth, qtl, kth, ktl, vt, 0);
    prep_split<<<4096, 256, 0, stream>>>(K, xh, xl);
    proj<<<512, 256, 0, stream>>>(xh, xl, V, wqh, wql, wkh, wkl, wv,
                                  qth, qtl, kth, ktl, vt, 1);
    attn_kernel<<<1024, 256, 0, stream>>>(qth, qtl, kth, ktl, vt, ao);
    oproj<<<256, 256, 0, stream>>>(ao, WO, (float*)d_out);
}